// Round 6
// baseline (1052.046 us; speedup 1.0000x reference)
//
#include <hip/hip_runtime.h>
#include <cstdint>
#include <cstddef>

#define B_ 512
#define T_ 2048
#define D_ 64
#define H_ 48
#define C_ 3

#define RECON_FLOATS ((size_t)B_ * T_ * D_)            // 67,108,864 floats (output 0)
#define LOGIT_FLOATS ((size_t)B_ * C_)                 // 1536 floats      (output 1)
#define Z_OFF        (RECON_FLOATS + LOGIT_FLOATS)     // z region         (output 2)
// u stash (f32, 50,331,648 floats) lives at out[0..) inside the recon region; dec overwrites it last.
#define ZSUM_STASH   (RECON_FLOATS - 32768)            // zsum stash, disjoint from u stash

// ---------------- encoder: u[b,t,h] = x row . Wenc^T + (benc+bmem); 1 row/thread, rolled d4 ----------------
__global__ __launch_bounds__(256) void k_enc(
    const float* __restrict__ x, const float* __restrict__ Wenc,
    const float* __restrict__ benc, const float* __restrict__ bmem,
    float* __restrict__ out)
{
    __shared__ float sW[16][48][4];   // sW[d4][h][c] = Wenc[h][4*d4+c] -> wave-uniform broadcast reads
    __shared__ float sb[48];
    const int tid = threadIdx.x;
    for (int idx = tid; idx < 48 * 64; idx += 256) {
        int h = idx >> 6, d = idx & 63;
        sW[d >> 2][h][d & 3] = Wenc[idx];
    }
    if (tid < 48) sb[tid] = benc[tid] + bmem[tid];
    __syncthreads();

    const size_t r = (size_t)blockIdx.x * 256 + tid;   // row (b,t)
    const float4* xr = reinterpret_cast<const float4*>(x + r * 64);

    float acc[48];
    #pragma unroll
    for (int h = 0; h < 48; ++h) acc[h] = sb[h];

    #pragma unroll 1
    for (int d4 = 0; d4 < 16; ++d4) {      // rolled: ~2KB body, L1I-resident
        const float4 xv = xr[d4];
        #pragma unroll
        for (int h = 0; h < 48; ++h) {
            const float4 wv = *reinterpret_cast<const float4*>(sW[d4][h]);
            acc[h] = fmaf(xv.x, wv.x, fmaf(xv.y, wv.y, fmaf(xv.z, wv.z, fmaf(xv.w, wv.w, acc[h]))));
        }
    }

    float4* dst = reinterpret_cast<float4*>(out + r * 48);
    #pragma unroll
    for (int j = 0; j < 12; ++j)
        dst[j] = make_float4(acc[4 * j], acc[4 * j + 1], acc[4 * j + 2], acc[4 * j + 3]);
}

// ---------------- recurrence: 1 wave per batch element; rolled step loop ----------------
__global__ __launch_bounds__(64) void k_rec(
    const float* __restrict__ Wmem, float* __restrict__ out)
{
    const int lane = threadIdx.x;
    const int b    = blockIdx.x;
    const int h    = lane < H_ ? lane : 0;

    // ms = 10*mem; 0.1 folded into wm:  ms' = 0.9*ms + wm.ms + u',  z = sigmoid(0.1*ms)
    float wm[48];
    #pragma unroll
    for (int j = 0; j < 48; ++j) wm[j] = 0.1f * Wmem[h * 48 + j];

    const float* ub = out + (size_t)b * T_ * 48;          // u stash (f32)
    float*       zb = out + Z_OFF + (size_t)b * T_ * 48;

    __shared__ float su[2][32 * 48];   // staging; lane owns global-linear [24*lane, 24*lane+24)

    float4 p[6];
    {
        const float4* s4 = reinterpret_cast<const float4*>(ub);
        #pragma unroll
        for (int k = 0; k < 6; ++k) p[k] = s4[lane * 6 + k];
        #pragma unroll
        for (int k = 0; k < 6; ++k)
            *reinterpret_cast<float4*>(&su[0][lane * 24 + 4 * k]) = p[k];
    }
    __syncthreads();

    float ms = 0.f, zs = 0.f;
    const float kExp = -0.14426950408889634f;  // -0.1 * log2(e)

    #pragma unroll 1
    for (int tile = 0; tile < T_ / 32; ++tile) {
        const int cur = tile & 1;
        const bool more = (tile + 1) < T_ / 32;

        // issue next-tile global loads first (long latency, hidden under the 32 steps)
        if (more) {
            const float4* n4 = reinterpret_cast<const float4*>(ub + (size_t)(tile + 1) * 32 * 48);
            #pragma unroll
            for (int k = 0; k < 6; ++k) p[k] = n4[lane * 6 + k];
        }

        const float* sut = su[cur];
        float*       zrow = zb + (size_t)tile * 32 * 48;

        #pragma unroll 1
        for (int s = 0; s < 32; ++s) {     // rolled: ~1KB body stays in L1I
            const float uuv = sut[s * 48 + h];   // ds_read issued at body top...
            float a0 = 0.9f * ms;                // leak folded into one chain
            float a1 = 0.f, a2 = 0.f, a3 = 0.f, a4 = 0.f, a5 = 0.f, a6 = 0.f, a7 = 0.f;
            #pragma unroll
            for (int g = 0; g < 6; ++g) {
                const int j = 8 * g;
                const float m0 = __int_as_float(__builtin_amdgcn_readlane(__float_as_int(ms), j + 0));
                const float m1 = __int_as_float(__builtin_amdgcn_readlane(__float_as_int(ms), j + 1));
                const float m2 = __int_as_float(__builtin_amdgcn_readlane(__float_as_int(ms), j + 2));
                const float m3 = __int_as_float(__builtin_amdgcn_readlane(__float_as_int(ms), j + 3));
                const float m4 = __int_as_float(__builtin_amdgcn_readlane(__float_as_int(ms), j + 4));
                const float m5 = __int_as_float(__builtin_amdgcn_readlane(__float_as_int(ms), j + 5));
                const float m6 = __int_as_float(__builtin_amdgcn_readlane(__float_as_int(ms), j + 6));
                const float m7 = __int_as_float(__builtin_amdgcn_readlane(__float_as_int(ms), j + 7));
                a0 = fmaf(m0, wm[j + 0], a0);
                a1 = fmaf(m1, wm[j + 1], a1);
                a2 = fmaf(m2, wm[j + 2], a2);
                a3 = fmaf(m3, wm[j + 3], a3);
                a4 = fmaf(m4, wm[j + 4], a4);
                a5 = fmaf(m5, wm[j + 5], a5);
                a6 = fmaf(m6, wm[j + 6], a6);
                a7 = fmaf(m7, wm[j + 7], a7);
            }
            const float dot = ((a0 + a1) + (a2 + a3)) + ((a4 + a5) + (a6 + a7));
            ms = dot + uuv;                      // ...and consumed here (latency hidden)
            // dead-end ops (never feed back): approx rcp is safe
            const float e = __builtin_amdgcn_exp2f(ms * kExp);
            const float z = __builtin_amdgcn_rcpf(1.0f + e);
            if (lane < H_) {
                zrow[s * 48 + lane] = z;
                zs += z;
            }
        }

        if (more) {
            #pragma unroll
            for (int k = 0; k < 6; ++k)
                *reinterpret_cast<float4*>(&su[cur ^ 1][lane * 24 + 4 * k]) = p[k];
            __syncthreads();   // single wave: cheap; orders DS writes vs next tile's reads
        }
    }

    if (lane < H_) out[ZSUM_STASH + (size_t)b * 48 + lane] = zs;
}

// ---------------- classifier (before dec overwrites the zsum stash) ----------------
__global__ __launch_bounds__(256) void k_cls(
    const float* __restrict__ Wcls, const float* __restrict__ bcls,
    float* __restrict__ out)
{
    const int g = blockIdx.x * 256 + threadIdx.x;
    if (g >= B_ * C_) return;
    const int b = g / C_, c = g - b * C_;
    const float* zsum = out + ZSUM_STASH + (size_t)b * 48;
    float acc = 0.f;
    #pragma unroll
    for (int hh = 0; hh < 48; ++hh) acc = fmaf(zsum[hh], Wcls[c * 48 + hh], acc);
    out[RECON_FLOATS + g] = acc * (1.0f / (float)T_) + bcls[c];
}

// ---------------- decoder: recon row = z row . Wdec^T + bdec; 1 row/thread, rolled dq ----------------
__global__ __launch_bounds__(256) void k_dec(
    const float* __restrict__ Wdec, const float* __restrict__ bdec,
    float* __restrict__ out)
{
    __shared__ float sW[12][64][4];   // sW[h4][d][c] = Wdec[d][4*h4+c] -> broadcast reads
    __shared__ float sb[64];
    const int tid = threadIdx.x;
    for (int idx = tid; idx < 64 * 48; idx += 256) {
        int d = idx / 48, hh = idx - d * 48;
        sW[hh >> 2][d][hh & 3] = Wdec[idx];
    }
    if (tid < 64) sb[tid] = bdec[tid];
    __syncthreads();

    const size_t r = (size_t)blockIdx.x * 256 + tid;
    const float* zr = out + Z_OFF + r * 48;
    float zrow[48];
    #pragma unroll
    for (int i = 0; i < 12; ++i)
        *reinterpret_cast<float4*>(&zrow[4 * i]) = *reinterpret_cast<const float4*>(zr + 4 * i);

    float* rr = out + r * 64;
    #pragma unroll 1
    for (int dq = 0; dq < 16; ++dq) {      // rolled: ~2KB body
        float4 o;
        #pragma unroll
        for (int c = 0; c < 4; ++c) {
            const int d = dq * 4 + c;
            float a0 = sb[d], a1 = 0.f, a2 = 0.f, a3 = 0.f;
            #pragma unroll
            for (int h4 = 0; h4 < 12; ++h4) {
                const float4 wv = *reinterpret_cast<const float4*>(sW[h4][d]);
                a0 = fmaf(zrow[4 * h4 + 0], wv.x, a0);
                a1 = fmaf(zrow[4 * h4 + 1], wv.y, a1);
                a2 = fmaf(zrow[4 * h4 + 2], wv.z, a2);
                a3 = fmaf(zrow[4 * h4 + 3], wv.w, a3);
            }
            (&o.x)[c] = (a0 + a1) + (a2 + a3);
        }
        *reinterpret_cast<float4*>(rr + dq * 4) = o;
    }
}

extern "C" void kernel_launch(void* const* d_in, const int* in_sizes, int n_in,
                              void* d_out, int out_size, void* d_ws, size_t ws_size,
                              hipStream_t stream) {
    const float* x    = (const float*)d_in[0];
    const float* Wenc = (const float*)d_in[1];
    const float* benc = (const float*)d_in[2];
    const float* Wmem = (const float*)d_in[3];
    const float* bmem = (const float*)d_in[4];
    const float* Wdec = (const float*)d_in[5];
    const float* bdec = (const float*)d_in[6];
    const float* Wcls = (const float*)d_in[7];
    const float* bcls = (const float*)d_in[8];
    float* out = (float*)d_out;

    const int blocks1 = (B_ * T_) / 256;            // 4096 blocks, 1 row/thread
    k_enc<<<dim3(blocks1), dim3(256), 0, stream>>>(x, Wenc, benc, bmem, out);
    k_rec<<<dim3(B_), dim3(64), 0, stream>>>(Wmem, out);
    k_cls<<<dim3((B_ * C_ + 255) / 256), dim3(256), 0, stream>>>(Wcls, bcls, out);
    k_dec<<<dim3(blocks1), dim3(256), 0, stream>>>(Wdec, bdec, out);
}